// Round 2
// baseline (161.697 us; speedup 1.0000x reference)
//
#include <hip/hip_runtime.h>
#include <cstdint>
#include <cstddef>
#include <math.h>

typedef unsigned long long u64;

#define BB 4
#define NN 32768
#define DD 512
#define KK 8192
#define TILE 8192

// ---------------- score kernel: one wave per row ----------------
__global__ __launch_bounds__(256) void score_kernel(const float* __restrict__ h,
                                                    const float* __restrict__ sf,
                                                    u64* __restrict__ keys) {
    int gw   = (blockIdx.x * 256 + threadIdx.x) >> 6;  // global wave id, 0..131071
    int lane = threadIdx.x & 63;
    int b = gw >> 15;          // / 32768
    int n = gw & (NN - 1);
    const float4* h4 = (const float4*)(h + ((size_t)b * NN + n) * DD);
    const float4* s4 = (const float4*)(sf + (size_t)b * DD);
    double acc = 0.0;
#pragma unroll
    for (int c = 0; c < 2; ++c) {
        float4 a = h4[lane + 64 * c];
        float4 w = s4[lane + 64 * c];
        acc += (double)a.x * w.x + (double)a.y * w.y +
               (double)a.z * w.z + (double)a.w * w.w;
    }
#pragma unroll
    for (int off = 32; off >= 1; off >>= 1)
        acc += __shfl_xor(acc, off, 64);
    if (lane == 0) {
        // Replicate the f32 reference pipeline exactly: f32 logit, f32 expf,
        // f32 add, f32 div. This reproduces the reference's tie-bucket
        // structure near sigmoid saturation (only even-ulp values near 1.0).
        float x = (float)acc;
        float e = expf(-x);
        float s = 1.0f / (1.0f + e);
        unsigned sb = __float_as_uint(s);
        u64 key = ((u64)(~sb) << 32) | (unsigned)n;   // asc u64 == desc score, ties by asc idx
        keys[((size_t)b << 15) + n] = key;
    }
}

// ------------- local bitonic sort of one 8192-tile (stages 2..8192) -------------
__global__ __launch_bounds__(1024) void local_sort_kernel(u64* __restrict__ keys) {
    __shared__ u64 tile[TILE];
    int b = blockIdx.x >> 2;
    int t = blockIdx.x & 3;
    u64* kb = keys + ((size_t)b << 15) + t * TILE;
    int tid = threadIdx.x;
    for (int i = tid; i < TILE; i += 1024) tile[i] = kb[i];
    __syncthreads();
    int gbase = t * TILE;
    for (int stage = 2; stage <= TILE; stage <<= 1) {
        for (int j = stage >> 1; j >= 1; j >>= 1) {
#pragma unroll
            for (int q = 0; q < 4; ++q) {
                int p = tid + q * 1024;                       // pair id 0..4095
                int i = ((p & ~(j - 1)) << 1) | (p & (j - 1));
                int l = i | j;
                bool asc = (((gbase + i) & stage) == 0);
                u64 a = tile[i], c = tile[l];
                if ((a > c) == asc) { tile[i] = c; tile[l] = a; }
            }
            __syncthreads();
        }
    }
    for (int i = tid; i < TILE; i += 1024) kb[i] = tile[i];
}

// ------------- one global compare-exchange pass (cross-tile strides) -------------
__global__ __launch_bounds__(256) void global_ce_kernel(u64* __restrict__ keys,
                                                        int stage, int j) {
    int pid = blockIdx.x * 256 + threadIdx.x;   // 0..65535  (4 batches x 16384 pairs)
    int b = pid >> 14;
    int p = pid & 16383;
    u64* kb = keys + ((size_t)b << 15);
    int i = ((p & ~(j - 1)) << 1) | (p & (j - 1));
    int l = i | j;
    bool asc = ((i & stage) == 0);
    u64 a = kb[i], c = kb[l];
    if ((a > c) == asc) { kb[i] = c; kb[l] = a; }
}

// ------------- finish a stage: passes j=4096..1 inside each tile -------------
__global__ __launch_bounds__(1024) void local_sweep_kernel(u64* __restrict__ keys,
                                                           int stage) {
    __shared__ u64 tile[TILE];
    int b = blockIdx.x >> 2;
    int t = blockIdx.x & 3;
    u64* kb = keys + ((size_t)b << 15) + t * TILE;
    int tid = threadIdx.x;
    for (int i = tid; i < TILE; i += 1024) tile[i] = kb[i];
    __syncthreads();
    int gbase = t * TILE;
    for (int j = 4096; j >= 1; j >>= 1) {
#pragma unroll
        for (int q = 0; q < 4; ++q) {
            int p = tid + q * 1024;
            int i = ((p & ~(j - 1)) << 1) | (p & (j - 1));
            int l = i | j;
            bool asc = (((gbase + i) & stage) == 0);
            u64 a = tile[i], c = tile[l];
            if ((a > c) == asc) { tile[i] = c; tile[l] = a; }
        }
        __syncthreads();
    }
    for (int i = tid; i < TILE; i += 1024) kb[i] = tile[i];
}

// ---------------- gather + scale: one wave per output row ----------------
__global__ __launch_bounds__(256) void gather_kernel(const float* __restrict__ h,
                                                     const u64* __restrict__ keys,
                                                     float* __restrict__ out) {
    int gw   = (blockIdx.x * 256 + threadIdx.x) >> 6;  // 0..32767
    int lane = threadIdx.x & 63;
    int b = gw >> 13;          // / 8192
    int j = gw & (KK - 1);
    u64 key = keys[((size_t)b << 15) + j];
    unsigned sb = ~(unsigned)(key >> 32);
    float v = __uint_as_float(sb);
    int idx = (int)(unsigned)(key & 0xFFFFFFFFu);
    const float4* src = (const float4*)(h + ((size_t)b * NN + idx) * DD);
    float4* dst = (float4*)(out + ((size_t)b * KK + j) * DD);
#pragma unroll
    for (int c = 0; c < 2; ++c) {
        float4 x = src[lane + 64 * c];
        x.x *= v; x.y *= v; x.z *= v; x.w *= v;
        dst[lane + 64 * c] = x;
    }
}

extern "C" void kernel_launch(void* const* d_in, const int* in_sizes, int n_in,
                              void* d_out, int out_size, void* d_ws, size_t ws_size,
                              hipStream_t stream) {
    const float* h  = (const float*)d_in[0];
    const float* sf = (const float*)d_in[1];
    float* out = (float*)d_out;
    u64* keys = (u64*)d_ws;    // needs 4*32768*8 = 1 MiB

    score_kernel<<<(BB * NN) / 4, 256, 0, stream>>>(h, sf, keys);
    local_sort_kernel<<<BB * 4, 1024, 0, stream>>>(keys);
    global_ce_kernel<<<256, 256, 0, stream>>>(keys, 16384, 8192);
    local_sweep_kernel<<<BB * 4, 1024, 0, stream>>>(keys, 16384);
    global_ce_kernel<<<256, 256, 0, stream>>>(keys, 32768, 16384);
    global_ce_kernel<<<256, 256, 0, stream>>>(keys, 32768, 8192);
    local_sweep_kernel<<<BB * 4, 1024, 0, stream>>>(keys, 32768);
    gather_kernel<<<(BB * KK) / 4, 256, 0, stream>>>(h, keys, out);
}

// Round 3
// 154.314 us; speedup vs baseline: 1.0478x; 1.0478x over previous
//
#include <hip/hip_runtime.h>
#include <cstdint>
#include <cstddef>
#include <math.h>

typedef unsigned long long u64;

#define BB 4
#define NN 32768
#define DD 512
#define KK 8192
#define TILE 8192
#define LT 1024      // threads per sort/merge block
#define VE 8         // elements per thread (TILE / LT)

// ---------------- score kernel: one wave per row ----------------
__global__ __launch_bounds__(256) void score_kernel(const float* __restrict__ h,
                                                    const float* __restrict__ sf,
                                                    u64* __restrict__ keys) {
    int gw   = (blockIdx.x * 256 + threadIdx.x) >> 6;  // global wave id, 0..131071
    int lane = threadIdx.x & 63;
    int b = gw >> 15;          // / 32768
    int n = gw & (NN - 1);
    const float4* h4 = (const float4*)(h + ((size_t)b * NN + n) * DD);
    const float4* s4 = (const float4*)(sf + (size_t)b * DD);
    double acc = 0.0;
#pragma unroll
    for (int c = 0; c < 2; ++c) {
        float4 a = h4[lane + 64 * c];
        float4 w = s4[lane + 64 * c];
        acc += (double)a.x * w.x + (double)a.y * w.y +
               (double)a.z * w.z + (double)a.w * w.w;
    }
#pragma unroll
    for (int off = 32; off >= 1; off >>= 1)
        acc += __shfl_xor(acc, off, 64);
    if (lane == 0) {
        // f32 sigmoid pipeline — replicates the reference's tie-bucket
        // structure near saturation (validated round 2; do not change).
        float x = (float)acc;
        float e = expf(-x);
        float s = 1.0f / (1.0f + e);
        unsigned sb = __float_as_uint(s);
        u64 key = ((u64)(~sb) << 32) | (unsigned)n;   // asc u64 == desc score, ties asc idx
        keys[((size_t)b << 15) + n] = key;
    }
}

// ---------------- register-resident bitonic primitives ----------------
// Element i = VE*t + e. CE rule: lower = ((i&j)==0), up = ((i&stage)==0);
// take-min iff (lower == up).

__device__ __forceinline__ void reg_pass(u64 v[VE], int base, int stage, int j) {
#pragma unroll
    for (int e = 0; e < VE; ++e) {
        if ((e & j) == 0) {
            int f = e | j;
            bool up = (((base + e) & stage) == 0);
            u64 a = v[e], b = v[f];
            bool sw = up ? (a > b) : (a < b);
            if (sw) { v[e] = b; v[f] = a; }
        }
    }
}

__device__ __forceinline__ void shfl_pass(u64 v[VE], int t, int base, int stage, int j) {
    int m = j >> 3;                       // lane xor mask (VE==8)
    bool lower = ((t & m) == 0);
#pragma unroll
    for (int e = 0; e < VE; ++e) {
        u64 pv = __shfl_xor(v[e], m, 64);
        bool up = (((base + e) & stage) == 0);
        bool tm = (lower == up);
        bool lt = v[e] < pv;
        v[e] = (tm == lt) ? v[e] : pv;
    }
}

__device__ __forceinline__ void lds_pass(u64 v[VE], unsigned* lo, unsigned* hi,
                                         int t, int base, int stage, int j) {
    __syncthreads();                      // protect WAR vs previous pass's reads
#pragma unroll
    for (int e = 0; e < VE; ++e) {
        lo[e * LT + t] = (unsigned)v[e];
        hi[e * LT + t] = (unsigned)(v[e] >> 32);
    }
    __syncthreads();
    int pt = t ^ (j >> 3);
    bool lower = ((t & (j >> 3)) == 0);
#pragma unroll
    for (int e = 0; e < VE; ++e) {
        u64 pv = ((u64)hi[e * LT + pt] << 32) | (u64)lo[e * LT + pt];
        bool up = (((base + e) & stage) == 0);
        bool tm = (lower == up);
        bool lt = v[e] < pv;
        v[e] = (tm == lt) ? v[e] : pv;
    }
}

// ------------- local full ascending sort of one 8192-tile -------------
__global__ __launch_bounds__(LT) void local_sort_kernel(u64* __restrict__ keys) {
    __shared__ unsigned lds_lo[TILE];
    __shared__ unsigned lds_hi[TILE];
    int b = blockIdx.x >> 2;
    int tile = blockIdx.x & 3;
    u64* kb = keys + ((size_t)b << 15) + tile * TILE;
    int t = threadIdx.x;
    int base = t * VE;
    u64 v[VE];
#pragma unroll
    for (int q = 0; q < VE / 2; ++q) {
        ulonglong2 p = ((const ulonglong2*)(kb + base))[q];
        v[2 * q] = p.x; v[2 * q + 1] = p.y;
    }
    for (int stage = 2; stage <= TILE; stage <<= 1) {
        int j = stage >> 1;
        for (; j >= 512; j >>= 1) lds_pass(v, lds_lo, lds_hi, t, base, stage, j);
        for (; j >= 8; j >>= 1)   shfl_pass(v, t, base, stage, j);
        for (; j >= 1; j >>= 1)   reg_pass(v, base, stage, j);
    }
#pragma unroll
    for (int q = 0; q < VE / 2; ++q) {
        ulonglong2 p; p.x = v[2 * q]; p.y = v[2 * q + 1];
        ((ulonglong2*)(kb + base))[q] = p;
    }
}

// ------------- top-8192 merge of two ascending 8192 runs, in-place into A -------------
// A = batch_base + p*2*boff, B = A + boff. C[i] = min(A[i], B[8191-i]) is bitonic
// and holds the 8192 smallest keys; a 13-pass ascending sweep sorts it.
__global__ __launch_bounds__(LT) void merge_topk_kernel(u64* __restrict__ keys,
                                                        int pshift, int boff) {
    __shared__ unsigned lds_lo[TILE];
    __shared__ unsigned lds_hi[TILE];
    int b = blockIdx.x >> pshift;
    int p = blockIdx.x & ((1 << pshift) - 1);
    u64* A = keys + ((size_t)b << 15) + (size_t)p * 2 * boff;
    u64* B = A + boff;
    int t = threadIdx.x;
    int base = t * VE;
    u64 a[VE], rb[VE], v[VE];
#pragma unroll
    for (int q = 0; q < VE / 2; ++q) {
        ulonglong2 pa = ((const ulonglong2*)(A + base))[q];
        a[2 * q] = pa.x; a[2 * q + 1] = pa.y;
        ulonglong2 pb = ((const ulonglong2*)(B + (TILE - VE - base)))[q];
        rb[2 * q] = pb.x; rb[2 * q + 1] = pb.y;
    }
#pragma unroll
    for (int e = 0; e < VE; ++e) {
        u64 x = a[e], y = rb[VE - 1 - e];       // y = B[TILE-1-(base+e)]
        v[e] = x < y ? x : y;
    }
    const int stage = 2 * TILE;                  // up == true everywhere
    int j = TILE >> 1;
    for (; j >= 512; j >>= 1) lds_pass(v, lds_lo, lds_hi, t, base, stage, j);
    for (; j >= 8; j >>= 1)   shfl_pass(v, t, base, stage, j);
    for (; j >= 1; j >>= 1)   reg_pass(v, base, stage, j);
#pragma unroll
    for (int q = 0; q < VE / 2; ++q) {
        ulonglong2 pv; pv.x = v[2 * q]; pv.y = v[2 * q + 1];
        ((ulonglong2*)(A + base))[q] = pv;
    }
}

// ---------------- gather + scale: one wave per output row ----------------
__global__ __launch_bounds__(256) void gather_kernel(const float* __restrict__ h,
                                                     const u64* __restrict__ keys,
                                                     float* __restrict__ out) {
    int gw   = (blockIdx.x * 256 + threadIdx.x) >> 6;  // 0..32767
    int lane = threadIdx.x & 63;
    int b = gw >> 13;          // / 8192
    int j = gw & (KK - 1);
    u64 key = keys[((size_t)b << 15) + j];
    unsigned sb = ~(unsigned)(key >> 32);
    float v = __uint_as_float(sb);
    int idx = (int)(unsigned)(key & 0xFFFFFFFFu);
    const float4* src = (const float4*)(h + ((size_t)b * NN + idx) * DD);
    float4* dst = (float4*)(out + ((size_t)b * KK + j) * DD);
#pragma unroll
    for (int c = 0; c < 2; ++c) {
        float4 x = src[lane + 64 * c];
        x.x *= v; x.y *= v; x.z *= v; x.w *= v;
        dst[lane + 64 * c] = x;
    }
}

extern "C" void kernel_launch(void* const* d_in, const int* in_sizes, int n_in,
                              void* d_out, int out_size, void* d_ws, size_t ws_size,
                              hipStream_t stream) {
    const float* h  = (const float*)d_in[0];
    const float* sf = (const float*)d_in[1];
    float* out = (float*)d_out;
    u64* keys = (u64*)d_ws;    // 4*32768*8 = 1 MiB

    score_kernel<<<(BB * NN) / 4, 256, 0, stream>>>(h, sf, keys);
    local_sort_kernel<<<BB * 4, LT, 0, stream>>>(keys);
    merge_topk_kernel<<<BB * 2, LT, 0, stream>>>(keys, 1, TILE);      // 4 runs -> 2
    merge_topk_kernel<<<BB * 1, LT, 0, stream>>>(keys, 0, 2 * TILE);  // 2 runs -> 1
    gather_kernel<<<(BB * KK) / 4, 256, 0, stream>>>(h, keys, out);
}